// Round 1
// baseline (9.935 us; speedup 1.0000x reference)
//
#include <hip/hip_runtime.h>

// QuantumQCNN analytic collapse:
//   After RX encoding, state is a product state; CNOTs only permute basis
//   states and RZ only adds phases, so basis probabilities are a permutation
//   of the product-state probabilities. Two CNOT chains map measured bit j
//   to XOR of input bits {i <= j, i == j (mod 2)}; independence gives
//     <Z_j> = prod_{i<=j, i==j mod 2} cos(x_i).
//   Then out = sigmoid(expz @ W^T + b).

__global__ __launch_bounds__(256) void qcnn_kernel(
    const float* __restrict__ in,   // [B, 8]
    const float* __restrict__ W,    // [4, 8]
    const float* __restrict__ bias, // [4]
    float* __restrict__ out,        // [B, 4]
    int B)
{
    int b = blockIdx.x * blockDim.x + threadIdx.x;
    if (b >= B) return;

    // vectorized load of the 8 per-sample angles (row is 32B-aligned)
    const float4* inv = reinterpret_cast<const float4*>(in) + (size_t)b * 2;
    float4 v0 = inv[0];
    float4 v1 = inv[1];
    float x[8] = {v0.x, v0.y, v0.z, v0.w, v1.x, v1.y, v1.z, v1.w};

    // expz[j] = parity-class prefix product of cos(x_i)
    float ez[8];
    float pe = 1.0f, po = 1.0f;
#pragma unroll
    for (int i = 0; i < 8; ++i) {
        float c = __cosf(x[i]);
        if ((i & 1) == 0) { pe *= c; ez[i] = pe; }
        else             { po *= c; ez[i] = po; }
    }

    // out[j] = sigmoid(sum_i ez[i] * W[j,i] + bias[j])
    float4 o;
    float* op = &o.x;
#pragma unroll
    for (int j = 0; j < 4; ++j) {
        float acc = bias[j];
#pragma unroll
        for (int i = 0; i < 8; ++i) acc += ez[i] * W[j * 8 + i];
        op[j] = 1.0f / (1.0f + __expf(-acc));
    }
    reinterpret_cast<float4*>(out)[b] = o;
}

extern "C" void kernel_launch(void* const* d_in, const int* in_sizes, int n_in,
                              void* d_out, int out_size, void* d_ws, size_t ws_size,
                              hipStream_t stream) {
    const float* inputs = (const float*)d_in[0];   // [B, 8]
    // d_in[1] = rz_params — provably irrelevant to the measurement (diagonal phases)
    const float* W      = (const float*)d_in[2];   // [4, 8]
    const float* bias   = (const float*)d_in[3];   // [4]
    float* out = (float*)d_out;

    int B = in_sizes[0] / 8;
    int block = 256;
    int grid = (B + block - 1) / block;
    qcnn_kernel<<<grid, block, 0, stream>>>(inputs, W, bias, out, B);
}

// Round 2
// 9.754 us; speedup vs baseline: 1.0185x; 1.0185x over previous
//
#include <hip/hip_runtime.h>

// QuantumQCNN analytic collapse:
//   After RX encoding, state is a product state; CNOTs only permute basis
//   states and RZ only adds phases, so basis probabilities are a permutation
//   of the product-state probabilities. Two CNOT chains map measured bit j
//   to XOR of input bits {i <= j, i == j (mod 2)}; independence gives
//     <Z_j> = prod_{i<=j, i==j mod 2} cos(x_i).
//   Then out = sigmoid(expz @ W^T + b).
//
// R2 probe: 2 samples/thread (independent chains) to test whether dur_us is
// kernel-bound or launch-overhead-bound. Traffic unchanged (6.3 MB total).

__device__ __forceinline__ void qcnn_sample(const float4 v0, const float4 v1,
                                            const float* __restrict__ W,
                                            const float* __restrict__ bias,
                                            float4* outp)
{
    float x[8] = {v0.x, v0.y, v0.z, v0.w, v1.x, v1.y, v1.z, v1.w};

    // expz[i] = parity-class prefix product of cos(x_i)
    float ez[8];
    float pe = 1.0f, po = 1.0f;
#pragma unroll
    for (int i = 0; i < 8; ++i) {
        float c = __cosf(x[i]);
        if ((i & 1) == 0) { pe *= c; ez[i] = pe; }
        else             { po *= c; ez[i] = po; }
    }

    float4 o;
    float* op = &o.x;
#pragma unroll
    for (int j = 0; j < 4; ++j) {
        float acc = bias[j];
#pragma unroll
        for (int i = 0; i < 8; ++i) acc += ez[i] * W[j * 8 + i];
        op[j] = 1.0f / (1.0f + __expf(-acc));
    }
    *outp = o;
}

__global__ __launch_bounds__(256) void qcnn_kernel2(
    const float* __restrict__ in,   // [B, 8]
    const float* __restrict__ W,    // [4, 8]
    const float* __restrict__ bias, // [4]
    float* __restrict__ out,        // [B, 4]
    int B)
{
    int t = blockIdx.x * blockDim.x + threadIdx.x;
    int b0 = t * 2;                 // two consecutive samples per thread
    if (b0 >= B) return;

    const float4* inv = reinterpret_cast<const float4*>(in) + (size_t)b0 * 2;
    // issue all 4 loads up front (independent chains)
    float4 a0 = inv[0];
    float4 a1 = inv[1];
    float4 c0 = inv[2];
    float4 c1 = inv[3];

    float4 o0, o1;
    qcnn_sample(a0, a1, W, bias, &o0);
    qcnn_sample(c0, c1, W, bias, &o1);

    float4* outv = reinterpret_cast<float4*>(out) + b0;
    outv[0] = o0;
    outv[1] = o1;
}

extern "C" void kernel_launch(void* const* d_in, const int* in_sizes, int n_in,
                              void* d_out, int out_size, void* d_ws, size_t ws_size,
                              hipStream_t stream) {
    const float* inputs = (const float*)d_in[0];   // [B, 8]
    // d_in[1] = rz_params — provably irrelevant (diagonal phases drop out of |amp|^2)
    const float* W      = (const float*)d_in[2];   // [4, 8]
    const float* bias   = (const float*)d_in[3];   // [4]
    float* out = (float*)d_out;

    int B = in_sizes[0] / 8;                       // 131072
    int block = 256;
    int grid = (B / 2 + block - 1) / block;        // 2 samples per thread
    qcnn_kernel2<<<grid, block, 0, stream>>>(inputs, W, bias, out, B);
}